// Round 6
// baseline (1129.247 us; speedup 1.0000x reference)
//
#include <hip/hip_runtime.h>

#define NB 32
#define NT 120
#define NG 25
#define ND 256
#define NH 8
#define NHD 32
#define NBT (NB*NT)

typedef unsigned short u16;
typedef unsigned int u32;

typedef __bf16 bf16x8 __attribute__((ext_vector_type(8)));
typedef float  f32x4  __attribute__((ext_vector_type(4)));

// ---- ws split-weight plane offsets (u16 elements) ----
#define WS_QKV_HI 0
#define WS_QKV_LO 196608
#define WS_WO_HI  393216
#define WS_WO_LO  458752
#define WS_WFC_HI 524288
#define WS_WFC_LO 589824
#define WS_W_U16  655360
#define WS_W_BYTES (WS_W_U16 * 2ull)                 // 1,310,720 B
// ---- pipeline activation scratch in ws ----
#define QKV_SLICE 19200                              // 3*25*256 f32 per (b,t)
#define WS_QKVF_OFF WS_W_BYTES
#define WS_QKVF_BYTES ((unsigned long long)NBT * QKV_SLICE * 4ull)   // 294,912,000
#define WS_PIPE_BYTES (WS_W_BYTES + WS_QKVF_BYTES)   // ~296 MB

#define SB_A 264                                     // A-tile bf16 row stride
#define K1_SMEM  (67584 + 10000)                     // hs hi/lo [64][264] + adjf
#define K34_SMEM (67584 + 2048 + 512)                // hs + s_part[4][64][2] + mu/rsd

__device__ __forceinline__ float bf2f(u16 u) { return __uint_as_float(((u32)u) << 16); }
__device__ __forceinline__ u16 f2bf(float f) {   // round-to-nearest-even
    u32 x = __float_as_uint(f);
    return (u16)((x + 0x7FFFu + ((x >> 16) & 1u)) >> 16);
}
__device__ __forceinline__ void splitf(float v, u16& h, u16& l) {
    h = f2bf(v);
    l = f2bf(v - bf2f(h));   // residual ~2^-18 rel
}
__device__ __forceinline__ bf16x8 ld_bf8(const u16* p) {
    uint4 u = *(const uint4*)p;
    return __builtin_bit_cast(bf16x8, u);
}

// Build split-weight workspace: hi/lo bf16 planes, row-major [rows][256].
__global__ __launch_bounds__(256)
void prep_w(const float* __restrict__ Wq, const float* __restrict__ Wk,
            const float* __restrict__ Wv, const float* __restrict__ Wo,
            const float* __restrict__ Wfc, u16* __restrict__ ws) {
    int e = blockIdx.x * 256 + threadIdx.x;     // 0 .. 327679
    float v; int hi_base, lo_base, idx;
    if (e < 196608) {                            // stacked Q,K,V rows 0..767
        int n = e >> 8, k = e & 255;
        const float* W = (n < 256) ? Wq : (n < 512 ? Wk : Wv);
        v = W[(n & 255) * 256 + k];
        hi_base = WS_QKV_HI; lo_base = WS_QKV_LO; idx = e;
    } else if (e < 262144) {
        idx = e - 196608; v = Wo[idx];
        hi_base = WS_WO_HI; lo_base = WS_WO_LO;
    } else {
        idx = e - 262144; v = Wfc[idx];
        hi_base = WS_WFC_HI; lo_base = WS_WFC_LO;
    }
    u16 h, l; splitf(v, h, l);
    ws[hi_base + idx] = h;
    ws[lo_base + idx] = l;
}

// ============================ K1: h = adj@x, QKV = h@W^T + b ============================
// grid = 1920 pairs x 2 N-halves; block 512 thr; M=64 (2 slices), N=384, K=256.
__global__ __launch_bounds__(512, 3)
void k1_qkv(const float* __restrict__ x, const float* __restrict__ adj,
            const float* __restrict__ bq, const float* __restrict__ bk,
            const float* __restrict__ bv,
            const u16* __restrict__ ws, float* __restrict__ qkv)
{
    extern __shared__ char smem[];
    u16* hs_hi = (u16*)smem;                       // [64][264]
    u16* hs_lo = (u16*)(smem + 33792);
    float* adjf = (float*)(smem + 67584);

    const int bt0 = (blockIdx.x >> 1) * 2;
    const int nh  = blockIdx.x & 1;
    const int tid = threadIdx.x;
    const int d = tid & 255, rep = tid >> 8;       // rep = slice in pair
    const int lane = tid & 63, wid = tid >> 6;
    const int lm = lane & 15, quad = lane >> 4;

    for (int i = tid; i < NG * NG; i += 512) adjf[i] = adj[i];
    __syncthreads();

    {   // h for slice rep, split-bf16 into A-tile
        const long xb = (long)(bt0 + rep) * (NG * ND);
        float acc[NG];
        #pragma unroll
        for (int g = 0; g < NG; ++g) acc[g] = 0.f;
        #pragma unroll
        for (int n = 0; n < NG; ++n) {
            const float xv = x[xb + n * ND + d];
            #pragma unroll
            for (int g = 0; g < NG; ++g) acc[g] += adjf[g * NG + n] * xv;
        }
        #pragma unroll
        for (int g = 0; g < NG; ++g) {
            u16 h, l; splitf(acc[g], h, l);
            hs_hi[(rep * 32 + g) * SB_A + d] = h;
            hs_lo[(rep * 32 + g) * SB_A + d] = l;
        }
        #pragma unroll
        for (int g = NG; g < 32; ++g) {
            hs_hi[(rep * 32 + g) * SB_A + d] = 0;
            hs_lo[(rep * 32 + g) * SB_A + d] = 0;
        }
    }
    __syncthreads();

    const int mrow = (wid & 1) * 32;
    const int ncol = nh * 384 + (wid >> 1) * 96;   // wave owns 96 cols
    const u16* whi = ws + WS_QKV_HI;
    const u16* wlo = ws + WS_QKV_LO;

    f32x4 acc[2][6];
    #pragma unroll
    for (int mt = 0; mt < 2; ++mt)
        #pragma unroll
        for (int nt = 0; nt < 6; ++nt) acc[mt][nt] = (f32x4)0.f;

    auto loadA = [&](int k0, bf16x8 (&ah)[2], bf16x8 (&al)[2]) {
        const int koff = k0 + quad * 8;
        #pragma unroll
        for (int mt = 0; mt < 2; ++mt) {
            const int off = (mrow + mt * 16 + lm) * SB_A + koff;
            ah[mt] = ld_bf8(hs_hi + off);
            al[mt] = ld_bf8(hs_lo + off);
        }
    };
    auto loadB = [&](int k0, int c, bf16x8 (&bh)[3], bf16x8 (&bl)[3]) {
        const int koff = k0 + quad * 8;
        #pragma unroll
        for (int j = 0; j < 3; ++j) {
            const int n = ncol + (c * 3 + j) * 16 + lm;
            const int off = n * 256 + koff;
            bh[j] = ld_bf8(whi + off);
            bl[j] = ld_bf8(wlo + off);
        }
    };

    bf16x8 Ah[2][2], Al[2][2], Bh[2][3], Bl[2][3];
    loadA(0, Ah[0], Al[0]);
    loadB(0, 0, Bh[0], Bl[0]);
    #pragma unroll
    for (int s = 0; s < 16; ++s) {                 // s = k0idx*2 + chunk
        const int c = s & 1;
        const int cur = s & 1, nxt = cur ^ 1;
        const int ka = (s >> 1) & 1;
        if (s < 15) {
            const int sn = s + 1;
            loadB((sn >> 1) * 32, sn & 1, Bh[nxt], Bl[nxt]);
            if ((sn & 1) == 0) loadA((sn >> 1) * 32, Ah[(sn >> 1) & 1], Al[(sn >> 1) & 1]);
        }
        #pragma unroll
        for (int j = 0; j < 3; ++j)
            #pragma unroll
            for (int mt = 0; mt < 2; ++mt)
                acc[mt][c * 3 + j] = __builtin_amdgcn_mfma_f32_16x16x32_bf16(Ah[ka][mt], Bh[cur][j], acc[mt][c * 3 + j], 0, 0, 0);
        #pragma unroll
        for (int j = 0; j < 3; ++j)
            #pragma unroll
            for (int mt = 0; mt < 2; ++mt)
                acc[mt][c * 3 + j] = __builtin_amdgcn_mfma_f32_16x16x32_bf16(Al[ka][mt], Bh[cur][j], acc[mt][c * 3 + j], 0, 0, 0);
        #pragma unroll
        for (int j = 0; j < 3; ++j)
            #pragma unroll
            for (int mt = 0; mt < 2; ++mt)
                acc[mt][c * 3 + j] = __builtin_amdgcn_mfma_f32_16x16x32_bf16(Ah[ka][mt], Bl[cur][j], acc[mt][c * 3 + j], 0, 0, 0);
    }

    #pragma unroll
    for (int nt = 0; nt < 6; ++nt) {
        const int n = ncol + nt * 16 + lm;
        const int mat = n >> 8, dc = n & 255;
        const float bb = (mat == 0 ? bq : (mat == 1 ? bk : bv))[dc];
        #pragma unroll
        for (int mt = 0; mt < 2; ++mt)
            #pragma unroll
            for (int i = 0; i < 4; ++i) {
                const int r = mrow + mt * 16 + quad * 4 + i;
                const int g = r & 31, sl = r >> 5;
                if (g < NG)
                    qkv[(long)(bt0 + sl) * QKV_SLICE + mat * 6400 + g * 256 + dc]
                        = acc[mt][nt][i] + bb;
            }
    }
}

// ============================ K2: scores + softmax(G) + att ============================
__global__ __launch_bounds__(256)
void k2_attn(const float* __restrict__ qkv, float* __restrict__ att)
{
    __shared__ float ss[NG * 64];
    __shared__ float sm[4 * 64];
    const int bt = blockIdx.x, tid = threadIdx.x;
    const float* qb = qkv + (long)bt * QKV_SLICE;

    for (int i = tid; i < NG * 64; i += 256) {
        const int g = i >> 6, hh = i & 63;
        const float4* q4 = (const float4*)(qb + g * 256 + (hh >> 3) * NHD);
        const float4* k4 = (const float4*)(qb + 6400 + g * 256 + (hh & 7) * NHD);
        float s = 0.f;
        #pragma unroll
        for (int c = 0; c < 8; ++c) {
            const float4 qa = q4[c], ka = k4[c];
            s += qa.x * ka.x + qa.y * ka.y + qa.z * ka.z + qa.w * ka.w;
        }
        ss[i] = s * 0.17677669529663687f;   // 1/sqrt(32)
    }
    __syncthreads();

    {   // softmax over g (dim=1), 4 partitions x 64 cols
        const int col = tid & 63, part = tid >> 6;
        float m = -1e30f;
        for (int g = part; g < NG; g += 4) m = fmaxf(m, ss[g * 64 + col]);
        sm[part * 64 + col] = m;
        __syncthreads();
        const float cm = fmaxf(fmaxf(sm[col], sm[64 + col]), fmaxf(sm[128 + col], sm[192 + col]));
        __syncthreads();
        float den = 0.f;
        for (int g = part; g < NG; g += 4) {
            const float e = expf(ss[g * 64 + col] - cm);
            ss[g * 64 + col] = e;
            den += e;
        }
        sm[part * 64 + col] = den;
        __syncthreads();
        const float inv = 1.f / (sm[col] + sm[64 + col] + sm[128 + col] + sm[192 + col]);
        for (int g = part; g < NG; g += 4) ss[g * 64 + col] *= inv;
    }
    __syncthreads();

    {   // att = w @ V
        const int h1 = tid >> 5, hd = tid & 31;
        const float* Vp = qb + 12800;
        for (int g = 0; g < NG; ++g) {
            float a = 0.f;
            #pragma unroll
            for (int h2 = 0; h2 < NH; ++h2)
                a += ss[g * 64 + h1 * 8 + h2] * Vp[g * 256 + h2 * 32 + hd];
            att[(long)bt * (NG * ND) + g * 256 + tid] = a;
        }
    }
}

// ============== K3/K4: GEMM(+bias) + residual (+relu) + layernorm, per 2 slices ==============
// PHASE 0: out = norm1(att@Wo^T + bo + x)        -> x1
// PHASE 1: out = norm2(x1 + relu(x1@Wfc^T + bfc)) -> final
template<int PHASE>
__global__ __launch_bounds__(512, 3)
void k34_gemm(const float* __restrict__ ain, const float* __restrict__ resid,
              const float* __restrict__ bvec,
              const float* __restrict__ alpha, const float* __restrict__ beta,
              const u16* __restrict__ ws, float* __restrict__ outp)
{
    extern __shared__ char smem[];
    u16* hs_hi = (u16*)smem;                       // [64][264]
    u16* hs_lo = (u16*)(smem + 33792);
    float* s_part = (float*)(smem + 67584);        // [4 nw][64 r][2]
    float* s_mu   = (float*)(smem + 67584 + 2048); // [64]
    float* s_rsd  = s_mu + 64;

    const int bt0 = blockIdx.x * 2;
    const int tid = threadIdx.x;
    const int lane = tid & 63, wid = tid >> 6;
    const int lm = lane & 15, quad = lane >> 4;

    // stage + split A
    for (int idx = tid; idx < 64 * 256; idx += 512) {
        const int r = idx >> 8, dc = idx & 255;
        const int g = r & 31, sl = r >> 5;
        float v = 0.f;
        if (g < NG) v = ain[(long)(bt0 + sl) * (NG * ND) + g * 256 + dc];
        u16 h, l; splitf(v, h, l);
        hs_hi[r * SB_A + dc] = h;
        hs_lo[r * SB_A + dc] = l;
    }
    __syncthreads();

    const int mrow = (wid & 1) * 32;
    const int ncol = (wid >> 1) * 64;
    const u16* whi = ws + (PHASE ? WS_WFC_HI : WS_WO_HI);
    const u16* wlo = ws + (PHASE ? WS_WFC_LO : WS_WO_LO);

    f32x4 acc[2][4];
    #pragma unroll
    for (int mt = 0; mt < 2; ++mt)
        #pragma unroll
        for (int nt = 0; nt < 4; ++nt) acc[mt][nt] = (f32x4)0.f;

    auto loadA = [&](int k0, bf16x8 (&ah)[2], bf16x8 (&al)[2]) {
        const int koff = k0 + quad * 8;
        #pragma unroll
        for (int mt = 0; mt < 2; ++mt) {
            const int off = (mrow + mt * 16 + lm) * SB_A + koff;
            ah[mt] = ld_bf8(hs_hi + off);
            al[mt] = ld_bf8(hs_lo + off);
        }
    };
    auto loadB = [&](int k0, bf16x8 (&bh)[4], bf16x8 (&bl)[4]) {
        const int koff = k0 + quad * 8;
        #pragma unroll
        for (int j = 0; j < 4; ++j) {
            const int off = (ncol + j * 16 + lm) * 256 + koff;
            bh[j] = ld_bf8(whi + off);
            bl[j] = ld_bf8(wlo + off);
        }
    };

    bf16x8 Ah[2][2], Al[2][2], Bh[2][4], Bl[2][4];
    loadA(0, Ah[0], Al[0]);
    loadB(0, Bh[0], Bl[0]);
    #pragma unroll
    for (int s = 0; s < 8; ++s) {
        const int cur = s & 1, nxt = cur ^ 1;
        if (s < 7) {
            loadB((s + 1) * 32, Bh[nxt], Bl[nxt]);
            loadA((s + 1) * 32, Ah[nxt], Al[nxt]);
        }
        #pragma unroll
        for (int j = 0; j < 4; ++j)
            #pragma unroll
            for (int mt = 0; mt < 2; ++mt)
                acc[mt][j] = __builtin_amdgcn_mfma_f32_16x16x32_bf16(Ah[cur][mt], Bh[cur][j], acc[mt][j], 0, 0, 0);
        #pragma unroll
        for (int j = 0; j < 4; ++j)
            #pragma unroll
            for (int mt = 0; mt < 2; ++mt)
                acc[mt][j] = __builtin_amdgcn_mfma_f32_16x16x32_bf16(Al[cur][mt], Bh[cur][j], acc[mt][j], 0, 0, 0);
        #pragma unroll
        for (int j = 0; j < 4; ++j)
            #pragma unroll
            for (int mt = 0; mt < 2; ++mt)
                acc[mt][j] = __builtin_amdgcn_mfma_f32_16x16x32_bf16(Ah[cur][mt], Bl[cur][j], acc[mt][j], 0, 0, 0);
    }

    // epilogue: z = (bias+resid[+relu]) per C element, kept in regs
    float z[2][4][4];
    #pragma unroll
    for (int nt = 0; nt < 4; ++nt) {
        const int cb = ncol + nt * 16 + lm;
        const float bb = bvec[cb];
        #pragma unroll
        for (int mt = 0; mt < 2; ++mt)
            #pragma unroll
            for (int i = 0; i < 4; ++i) {
                const int r = mrow + mt * 16 + quad * 4 + i;
                const int g = r & 31, sl = r >> 5;
                float v = 0.f;
                if (g < NG) {
                    const float rv = resid[(long)(bt0 + sl) * (NG * ND) + g * 256 + cb];
                    const float cc = acc[mt][nt][i] + bb;
                    v = PHASE ? (rv + fmaxf(cc, 0.f)) : (cc + rv);
                }
                z[mt][nt][i] = v;
            }
    }
    // row stats: in-lane over nt, shuffle over lm (16 lanes), LDS over 4 n-waves
    #pragma unroll
    for (int mt = 0; mt < 2; ++mt)
        #pragma unroll
        for (int i = 0; i < 4; ++i) {
            float s = 0.f, q = 0.f;
            #pragma unroll
            for (int nt = 0; nt < 4; ++nt) { s += z[mt][nt][i]; q += z[mt][nt][i] * z[mt][nt][i]; }
            #pragma unroll
            for (int off = 1; off <= 8; off <<= 1) {
                s += __shfl_xor(s, off, 64);
                q += __shfl_xor(q, off, 64);
            }
            if (lm == 0) {
                const int r = mrow + mt * 16 + quad * 4 + i;
                s_part[(wid >> 1) * 128 + r * 2 + 0] = s;
                s_part[(wid >> 1) * 128 + r * 2 + 1] = q;
            }
        }
    __syncthreads();
    if (tid < 64) {
        float s = 0.f, q = 0.f;
        #pragma unroll
        for (int nw = 0; nw < 4; ++nw) {
            s += s_part[nw * 128 + tid * 2 + 0];
            q += s_part[nw * 128 + tid * 2 + 1];
        }
        const float mu = s * (1.f / 256.f);
        const float var = fmaxf((q - 256.f * mu * mu) * (1.f / 255.f), 0.f);  // ddof=1
        s_mu[tid] = mu;
        s_rsd[tid] = 1.f / (sqrtf(var) + 1e-6f);
    }
    __syncthreads();
    #pragma unroll
    for (int nt = 0; nt < 4; ++nt) {
        const int cb = ncol + nt * 16 + lm;
        const float af = alpha[cb], bf = beta[cb];
        #pragma unroll
        for (int mt = 0; mt < 2; ++mt)
            #pragma unroll
            for (int i = 0; i < 4; ++i) {
                const int r = mrow + mt * 16 + quad * 4 + i;
                const int g = r & 31, sl = r >> 5;
                if (g < NG)
                    outp[(long)(bt0 + sl) * (NG * ND) + g * 256 + cb]
                        = af * (z[mt][nt][i] - s_mu[r]) * s_rsd[r] + bf;
            }
    }
}

// ======================= fallback: R5 fused kernel (ws too small) =======================
#define NTH 512
#define SB 264
#define SF 268
#define OFF_HS_HI 0
#define OFF_HS_LO 16896
#define OFF_QKV   33792
#define OFF_ADJ   136704
#define OFF_SS    139312
#define OFF_WRED  145712
#define OFF_MU    146544
#define OFF_RSD   146656
#define SMEM_TOT  146768

__device__ __forceinline__ void norm_stats8(const float* zv, int gn,
                                            int lane, int wid, int tid,
                                            float (*s_wred)[13][2], float* s_mu, float* s_rsd) {
    #pragma unroll
    for (int i = 0; i < 13; ++i) {
        if (i >= gn) break;
        float s = zv[i], q = zv[i] * zv[i];
        #pragma unroll
        for (int off = 32; off > 0; off >>= 1) {
            s += __shfl_xor(s, off, 64);
            q += __shfl_xor(q, off, 64);
        }
        if (lane == 0) { s_wred[wid][i][0] = s; s_wred[wid][i][1] = q; }
    }
    __syncthreads();
    if (tid < NG) {
        const int g = tid;
        const int wb = (g < 13) ? 0 : 4, lg = (g < 13) ? g : g - 13;
        float s = 0.f, q = 0.f;
        #pragma unroll
        for (int w = 0; w < 4; ++w) { s += s_wred[wb + w][lg][0]; q += s_wred[wb + w][lg][1]; }
        float mu = s * (1.f / 256.f);
        float var = fmaxf((q - 256.f * mu * mu) * (1.f / 255.f), 0.f);
        s_mu[g] = mu;
        s_rsd[g] = 1.f / (sqrtf(var) + 1e-6f);
    }
    __syncthreads();
}

template<bool PREP>
__device__ __forceinline__ void load_bfrag(const u16* wshi, const u16* wslo,
                                           const float* Wf, int row, int koff,
                                           bf16x8& bh, bf16x8& bl) {
    if constexpr (PREP) {
        const int off = row * 256 + koff;
        bh = ld_bf8(wshi + off);
        bl = ld_bf8(wslo + off);
    } else {
        const float* p = Wf + row * 256 + koff;
        float4 w0 = *(const float4*)p, w1 = *(const float4*)(p + 4);
        float wv[8] = {w0.x, w0.y, w0.z, w0.w, w1.x, w1.y, w1.z, w1.w};
        union { u16 s[8]; bf16x8 v; } H, L;
        #pragma unroll
        for (int j = 0; j < 8; ++j) splitf(wv[j], H.s[j], L.s[j]);
        bh = H.v; bl = L.v;
    }
}

template<bool PREP>
__global__ __launch_bounds__(NTH, 2)
void enc_mfma(const float* __restrict__ x,  const float* __restrict__ adj,
              const float* __restrict__ Wq, const float* __restrict__ bq,
              const float* __restrict__ Wk, const float* __restrict__ bk,
              const float* __restrict__ Wv, const float* __restrict__ bv,
              const float* __restrict__ Wo, const float* __restrict__ bo,
              const float* __restrict__ Wfc,const float* __restrict__ bfc,
              const float* __restrict__ alpha, const float* __restrict__ beta,
              float* __restrict__ out, const u16* __restrict__ ws)
{
    extern __shared__ char smem[];
    u16*   hs_hi = (u16*)(smem + OFF_HS_HI);
    u16*   hs_lo = (u16*)(smem + OFF_HS_LO);
    float* qkvf  = (float*)(smem + OFF_QKV);
    float* adjf  = (float*)(smem + OFF_ADJ);
    float* ss    = (float*)(smem + OFF_SS);
    float (*s_wred)[13][2] = (float(*)[13][2])(smem + OFF_WRED);
    float* s_mu  = (float*)(smem + OFF_MU);
    float* s_rsd = (float*)(smem + OFF_RSD);

    const int bt = blockIdx.x;
    const int tid = threadIdx.x;
    const int d = tid & 255, rep = tid >> 8;
    const int lane = tid & 63, wid = tid >> 6;
    const int lm = lane & 15, quad = lane >> 4;
    const int g0 = rep ? 13 : 0, gn = rep ? 12 : 13;
    const long base = (long)bt * (NG * ND);

    auto loadA = [&](int k0, bf16x8 (&ah)[2], bf16x8 (&al)[2]) {
        const int koff = k0 + quad * 8;
        #pragma unroll
        for (int mt = 0; mt < 2; ++mt) {
            const int off = (mt * 16 + lm) * SB + koff;
            ah[mt] = ld_bf8(hs_hi + off);
            al[mt] = ld_bf8(hs_lo + off);
        }
    };
    auto loadB_qkv = [&](int k0, bf16x8 (&bh)[6], bf16x8 (&bl)[6]) {
        const int koff = k0 + quad * 8;
        #pragma unroll
        for (int j = 0; j < 6; ++j) {
            const int n0 = wid * 96 + j * 16;
            const int mat = n0 >> 8;
            const float* Wf = (mat == 0) ? Wq : (mat == 1 ? Wk : Wv);
            load_bfrag<PREP>(ws + WS_QKV_HI, ws + WS_QKV_LO, Wf,
                             PREP ? (n0 + lm) : ((n0 & 255) + lm), koff, bh[j], bl[j]);
        }
    };
    auto loadB_wo = [&](int k0, bf16x8 (&bh)[2], bf16x8 (&bl)[2]) {
        const int koff = k0 + quad * 8;
        #pragma unroll
        for (int j = 0; j < 2; ++j)
            load_bfrag<PREP>(ws + WS_WO_HI, ws + WS_WO_LO, Wo,
                             wid * 32 + j * 16 + lm, koff, bh[j], bl[j]);
    };
    auto loadB_wfc = [&](int k0, bf16x8 (&bh)[2], bf16x8 (&bl)[2]) {
        const int koff = k0 + quad * 8;
        #pragma unroll
        for (int j = 0; j < 2; ++j)
            load_bfrag<PREP>(ws + WS_WFC_HI, ws + WS_WFC_LO, Wfc,
                             wid * 32 + j * 16 + lm, koff, bh[j], bl[j]);
    };

    bf16x8 bh2[2][6], bl2[2][6];
    bf16x8 bh6[2][2], bl6[2][2];
    bf16x8 bh8[2][2], bl8[2][2];
    float zx[13];
    float zv[13];

    for (int i = tid; i < NG * NG; i += NTH) adjf[i] = adj[i];
    const float af = alpha[d], bef = beta[d];
    __syncthreads();

    {
        float acc[13];
        #pragma unroll
        for (int i = 0; i < 13; ++i) acc[i] = 0.f;
        #pragma unroll
        for (int n = 0; n < NG; ++n) {
            float xv = x[base + n * ND + d];
            if (rep == 0) { if (n < 13) zx[n] = xv; }
            else          { if (n >= 13) zx[n - 13] = xv; }
            #pragma unroll
            for (int i = 0; i < 13; ++i)
                acc[i] += adjf[(g0 + i) * NG + n] * xv;
        }
        #pragma unroll
        for (int i = 0; i < 13; ++i) {
            if (i >= gn) break;
            u16 h, l; splitf(acc[i], h, l);
            hs_hi[(g0 + i) * SB + d] = h; hs_lo[(g0 + i) * SB + d] = l;
        }
        if (rep) {
            #pragma unroll
            for (int g = NG; g < 32; ++g) { hs_hi[g * SB + d] = 0; hs_lo[g * SB + d] = 0; }
        }
    }
    loadB_qkv(0, bh2[0], bl2[0]);
    __syncthreads();

    {
        float bb[6];
        #pragma unroll
        for (int nt = 0; nt < 6; ++nt) {
            const int n0 = wid * 96 + nt * 16;
            const int mat = n0 >> 8, cb = (n0 & 255) + lm;
            const float* bp = (mat == 0) ? bq : (mat == 1 ? bk : bv);
            bb[nt] = bp[cb];
        }
        f32x4 acc[2][6];
        #pragma unroll
        for (int mt = 0; mt < 2; ++mt)
            #pragma unroll
            for (int nt = 0; nt < 6; ++nt) acc[mt][nt] = (f32x4)0.f;

        bf16x8 ah[2][2], al[2][2];
        loadA(0, ah[0], al[0]);
        #pragma unroll
        for (int ki = 0; ki < 8; ++ki) {
            const int cur = ki & 1, nxt = cur ^ 1;
            if (ki < 7) {
                loadB_qkv(32 * (ki + 1), bh2[nxt], bl2[nxt]);
                loadA(32 * (ki + 1), ah[nxt], al[nxt]);
            }
            #pragma unroll
            for (int j = 0; j < 6; ++j)
                #pragma unroll
                for (int mt = 0; mt < 2; ++mt)
                    acc[mt][j] = __builtin_amdgcn_mfma_f32_16x16x32_bf16(ah[cur][mt], bh2[cur][j], acc[mt][j], 0, 0, 0);
            #pragma unroll
            for (int j = 0; j < 6; ++j)
                #pragma unroll
                for (int mt = 0; mt < 2; ++mt)
                    acc[mt][j] = __builtin_amdgcn_mfma_f32_16x16x32_bf16(al[cur][mt], bh2[cur][j], acc[mt][j], 0, 0, 0);
            #pragma unroll
            for (int j = 0; j < 6; ++j)
                #pragma unroll
                for (int mt = 0; mt < 2; ++mt)
                    acc[mt][j] = __builtin_amdgcn_mfma_f32_16x16x32_bf16(ah[cur][mt], bl2[cur][j], acc[mt][j], 0, 0, 0);
        }
        #pragma unroll
        for (int nt = 0; nt < 6; ++nt) {
            const int n0 = wid * 96 + nt * 16;
            const int mat = n0 >> 8, cb = (n0 & 255) + lm;
            float* plane = qkvf + mat * (32 * SF);
            #pragma unroll
            for (int mt = 0; mt < 2; ++mt)
                #pragma unroll
                for (int i = 0; i < 4; ++i)
                    plane[(mt * 16 + quad * 4 + i) * SF + cb] = acc[mt][nt][i] + bb[nt];
        }
    }
    __syncthreads();

    for (int i = tid; i < NG * 64; i += NTH) {
        const int g = i >> 6, hh = i & 63;
        const float4* q4 = (const float4*)(qkvf + 0 * 32 * SF + g * SF + (hh >> 3) * NHD);
        const float4* k4 = (const float4*)(qkvf + 1 * 32 * SF + g * SF + (hh & 7) * NHD);
        float s = 0.f;
        #pragma unroll
        for (int c = 0; c < 8; ++c) {
            float4 qa = q4[c], ka = k4[c];
            s += qa.x * ka.x + qa.y * ka.y + qa.z * ka.z + qa.w * ka.w;
        }
        ss[i] = s * 0.17677669529663687f;
    }
    __syncthreads();

    {
        float* s_sm = adjf;
        const int col = tid & 63, part = tid >> 6;
        float m = -1e30f;
        for (int g = part; g < NG; g += 8) m = fmaxf(m, ss[g * 64 + col]);
        s_sm[part * 64 + col] = m;
        __syncthreads();
        float cm = -1e30f;
        #pragma unroll
        for (int p = 0; p < 8; ++p) cm = fmaxf(cm, s_sm[p * 64 + col]);
        __syncthreads();
        float den = 0.f;
        for (int g = part; g < NG; g += 8) {
            float e = expf(ss[g * 64 + col] - cm);
            ss[g * 64 + col] = e;
            den += e;
        }
        s_sm[part * 64 + col] = den;
        __syncthreads();
        float tden = 0.f;
        #pragma unroll
        for (int p = 0; p < 8; ++p) tden += s_sm[p * 64 + col];
        const float inv = 1.f / tden;
        for (int g = part; g < NG; g += 8) ss[g * 64 + col] *= inv;
    }
    __syncthreads();

    {
        const int h1 = (tid >> 5) & 7, hd = tid & 31;
        const float* Vp = qkvf + 2 * 32 * SF;
        #pragma unroll
        for (int i = 0; i < 13; ++i) {
            if (i >= gn) break;
            const int g = g0 + i;
            float a = 0.f;
            #pragma unroll
            for (int h2 = 0; h2 < NH; ++h2)
                a += ss[g * 64 + h1 * 8 + h2] * Vp[g * SF + h2 * NHD + hd];
            u16 h, l; splitf(a, h, l);
            hs_hi[g * SB + d] = h; hs_lo[g * SB + d] = l;
        }
    }
    loadB_wo(0, bh6[0], bl6[0]);
    __syncthreads();

    {
        float bb[2] = { bo[wid * 32 + lm], bo[wid * 32 + 16 + lm] };
        f32x4 acc[2][2];
        #pragma unroll
        for (int mt = 0; mt < 2; ++mt)
            #pragma unroll
            for (int nt = 0; nt < 2; ++nt) acc[mt][nt] = (f32x4)0.f;

        bf16x8 ah[2][2], al[2][2];
        loadA(0, ah[0], al[0]);
        #pragma unroll
        for (int ki = 0; ki < 8; ++ki) {
            const int cur = ki & 1, nxt = cur ^ 1;
            if (ki < 7) {
                loadB_wo(32 * (ki + 1), bh6[nxt], bl6[nxt]);
                loadA(32 * (ki + 1), ah[nxt], al[nxt]);
            }
            #pragma unroll
            for (int j = 0; j < 2; ++j)
                #pragma unroll
                for (int mt = 0; mt < 2; ++mt)
                    acc[mt][j] = __builtin_amdgcn_mfma_f32_16x16x32_bf16(ah[cur][mt], bh6[cur][j], acc[mt][j], 0, 0, 0);
            #pragma unroll
            for (int j = 0; j < 2; ++j)
                #pragma unroll
                for (int mt = 0; mt < 2; ++mt)
                    acc[mt][j] = __builtin_amdgcn_mfma_f32_16x16x32_bf16(al[cur][mt], bh6[cur][j], acc[mt][j], 0, 0, 0);
            #pragma unroll
            for (int j = 0; j < 2; ++j)
                #pragma unroll
                for (int mt = 0; mt < 2; ++mt)
                    acc[mt][j] = __builtin_amdgcn_mfma_f32_16x16x32_bf16(ah[cur][mt], bl6[cur][j], acc[mt][j], 0, 0, 0);
        }
        float* zs = qkvf;
        #pragma unroll
        for (int nt = 0; nt < 2; ++nt) {
            const int col = wid * 32 + nt * 16 + lm;
            #pragma unroll
            for (int mt = 0; mt < 2; ++mt)
                #pragma unroll
                for (int i = 0; i < 4; ++i)
                    zs[(mt * 16 + quad * 4 + i) * SF + col] = acc[mt][nt][i] + bb[nt];
        }
    }
    __syncthreads();

    {
        float* zs = qkvf;
        #pragma unroll
        for (int i = 0; i < 13; ++i) {
            if (i >= gn) break;
            zv[i] = zs[(g0 + i) * SF + d] + zx[i];
        }
    }
    norm_stats8(zv, gn, lane, wid, tid, s_wred, s_mu, s_rsd);
    #pragma unroll
    for (int i = 0; i < 13; ++i) {
        if (i >= gn) break;
        const float x1 = af * (zv[i] - s_mu[g0 + i]) * s_rsd[g0 + i] + bef;
        zv[i] = x1;
        u16 h, l; splitf(x1, h, l);
        hs_hi[(g0 + i) * SB + d] = h; hs_lo[(g0 + i) * SB + d] = l;
    }
    loadB_wfc(0, bh8[0], bl8[0]);
    __syncthreads();

    {
        float bb[2] = { bfc[wid * 32 + lm], bfc[wid * 32 + 16 + lm] };
        f32x4 acc[2][2];
        #pragma unroll
        for (int mt = 0; mt < 2; ++mt)
            #pragma unroll
            for (int nt = 0; nt < 2; ++nt) acc[mt][nt] = (f32x4)0.f;

        bf16x8 ah[2][2], al[2][2];
        loadA(0, ah[0], al[0]);
        #pragma unroll
        for (int ki = 0; ki < 8; ++ki) {
            const int cur = ki & 1, nxt = cur ^ 1;
            if (ki < 7) {
                loadB_wfc(32 * (ki + 1), bh8[nxt], bl8[nxt]);
                loadA(32 * (ki + 1), ah[nxt], al[nxt]);
            }
            #pragma unroll
            for (int j = 0; j < 2; ++j)
                #pragma unroll
                for (int mt = 0; mt < 2; ++mt)
                    acc[mt][j] = __builtin_amdgcn_mfma_f32_16x16x32_bf16(ah[cur][mt], bh8[cur][j], acc[mt][j], 0, 0, 0);
            #pragma unroll
            for (int j = 0; j < 2; ++j)
                #pragma unroll
                for (int mt = 0; mt < 2; ++mt)
                    acc[mt][j] = __builtin_amdgcn_mfma_f32_16x16x32_bf16(al[cur][mt], bh8[cur][j], acc[mt][j], 0, 0, 0);
            #pragma unroll
            for (int j = 0; j < 2; ++j)
                #pragma unroll
                for (int mt = 0; mt < 2; ++mt)
                    acc[mt][j] = __builtin_amdgcn_mfma_f32_16x16x32_bf16(ah[cur][mt], bl8[cur][j], acc[mt][j], 0, 0, 0);
        }
        float* zs = qkvf;
        #pragma unroll
        for (int nt = 0; nt < 2; ++nt) {
            const int col = wid * 32 + nt * 16 + lm;
            #pragma unroll
            for (int mt = 0; mt < 2; ++mt)
                #pragma unroll
                for (int i = 0; i < 4; ++i)
                    zs[(mt * 16 + quad * 4 + i) * SF + col] = fmaxf(acc[mt][nt][i] + bb[nt], 0.f);
        }
    }
    __syncthreads();

    float z2[13];
    {
        float* zs = qkvf;
        #pragma unroll
        for (int i = 0; i < 13; ++i) {
            if (i >= gn) break;
            z2[i] = zv[i] + zs[(g0 + i) * SF + d];
        }
    }
    norm_stats8(z2, gn, lane, wid, tid, s_wred, s_mu, s_rsd);
    #pragma unroll
    for (int i = 0; i < 13; ++i) {
        if (i >= gn) break;
        out[base + (g0 + i) * ND + d] = af * (z2[i] - s_mu[g0 + i]) * s_rsd[g0 + i] + bef;
    }
}

extern "C" void kernel_launch(void* const* d_in, const int* in_sizes, int n_in,
                              void* d_out, int out_size, void* d_ws, size_t ws_size,
                              hipStream_t stream) {
    (void)in_sizes; (void)n_in; (void)out_size;
    const float* x     = (const float*)d_in[0];
    const float* adj   = (const float*)d_in[1];
    const float* Wq    = (const float*)d_in[2];
    const float* bq    = (const float*)d_in[3];
    const float* Wk    = (const float*)d_in[4];
    const float* bk    = (const float*)d_in[5];
    const float* Wv    = (const float*)d_in[6];
    const float* bv    = (const float*)d_in[7];
    const float* Wo    = (const float*)d_in[8];
    const float* bo    = (const float*)d_in[9];
    const float* Wfc   = (const float*)d_in[10];
    const float* bfc   = (const float*)d_in[11];
    const float* alpha = (const float*)d_in[12];
    const float* beta  = (const float*)d_in[13];
    float* out = (float*)d_out;
    u16* ws = (u16*)d_ws;
    float* qkvf = (float*)((char*)d_ws + WS_QKVF_OFF);

    if (ws_size >= WS_PIPE_BYTES) {
        hipFuncSetAttribute((const void*)k1_qkv,
                            hipFuncAttributeMaxDynamicSharedMemorySize, K1_SMEM);
        hipFuncSetAttribute((const void*)k34_gemm<0>,
                            hipFuncAttributeMaxDynamicSharedMemorySize, K34_SMEM);
        hipFuncSetAttribute((const void*)k34_gemm<1>,
                            hipFuncAttributeMaxDynamicSharedMemorySize, K34_SMEM);
        prep_w<<<dim3(1280), dim3(256), 0, stream>>>(Wq, Wk, Wv, Wo, Wfc, ws);
        k1_qkv<<<dim3(NBT), dim3(512), K1_SMEM, stream>>>(x, adj, bq, bk, bv, ws, qkvf);
        k2_attn<<<dim3(NBT), dim3(256), 0, stream>>>(qkvf, out);              // att -> d_out
        k34_gemm<0><<<dim3(NBT / 2), dim3(512), K34_SMEM, stream>>>(
            out, x, bo, alpha, beta, ws, qkvf);                               // x1 -> qkv region
        k34_gemm<1><<<dim3(NBT / 2), dim3(512), K34_SMEM, stream>>>(
            qkvf, qkvf, bfc, alpha, beta, ws, out);                           // final -> d_out
    } else {
        hipFuncSetAttribute((const void*)enc_mfma<true>,
                            hipFuncAttributeMaxDynamicSharedMemorySize, SMEM_TOT);
        hipFuncSetAttribute((const void*)enc_mfma<false>,
                            hipFuncAttributeMaxDynamicSharedMemorySize, SMEM_TOT);
        if (ws_size >= WS_W_BYTES) {
            prep_w<<<dim3(1280), dim3(256), 0, stream>>>(Wq, Wk, Wv, Wo, Wfc, ws);
            enc_mfma<true><<<dim3(NBT), dim3(NTH), SMEM_TOT, stream>>>(
                x, adj, Wq, bq, Wk, bk, Wv, bv, Wo, bo, Wfc, bfc, alpha, beta, out, ws);
        } else {
            enc_mfma<false><<<dim3(NBT), dim3(NTH), SMEM_TOT, stream>>>(
                x, adj, Wq, bq, Wk, bk, Wv, bv, Wo, bo, Wfc, bfc, alpha, beta, out, ws);
        }
    }
}